// Round 6
// baseline (1026.626 us; speedup 1.0000x reference)
//
#include <hip/hip_runtime.h>

typedef unsigned short u16;
typedef __attribute__((ext_vector_type(2))) unsigned int u32x2;
typedef __attribute__((ext_vector_type(4))) unsigned int u32x4;
typedef __attribute__((ext_vector_type(4))) float f32x4;
typedef __attribute__((ext_vector_type(8))) short bf16x8;

__device__ __forceinline__ float bf2f(u16 u) {
    union { unsigned int i; float f; } v; v.i = ((unsigned int)u) << 16; return v.f;
}
__device__ __forceinline__ u16 f2bf(float f) {
    union { float f; unsigned int i; } v; v.f = f;
    unsigned int x = v.i;
    return (u16)((x + 0x7fffu + ((x >> 16) & 1u)) >> 16);
}
__device__ __forceinline__ unsigned int pack2(float a, float b) {
    return (unsigned int)f2bf(a) | ((unsigned int)f2bf(b) << 16);
}
__device__ __forceinline__ void split2(float a, float b, unsigned int& h, unsigned int& l) {
    u16 ha = f2bf(a), hb = f2bf(b);
    u16 la = f2bf(a - bf2f(ha)), lb = f2bf(b - bf2f(hb));
    h = (unsigned int)ha | ((unsigned int)hb << 16);
    l = (unsigned int)la | ((unsigned int)lb << 16);
}

__device__ __forceinline__ f32x4 MFMA(bf16x8 a, bf16x8 b, f32x4 c) {
    return __builtin_amdgcn_mfma_f32_16x16x32_bf16(a, b, c, 0, 0, 0);
}

// ---------------------------------------------------------------------------
// kprep: Wcomb[hg][k] = invt_h * sum_d Wslice[g,d]*Wx[h*32+d,k]  (bf16)
//        bcomb[hg]    = invt_h * (sum_d Wslice[g,d]*bx[h*32+d] + bslice[g])
//        WfxT = bf16(Wfx)
// ---------------------------------------------------------------------------
__global__ __launch_bounds__(256) void kprep(
    const float* __restrict__ Wx, const float* __restrict__ bx,
    const float* __restrict__ Wfx, const float* __restrict__ Wslice,
    const float* __restrict__ bslice, const float* __restrict__ temperature,
    u16* __restrict__ Wcomb, float* __restrict__ bcomb, u16* __restrict__ WfxT)
{
    const int gidx = blockIdx.x * 256 + threadIdx.x;
    if (gidx < 131072) {
        const int hg = gidx >> 8, k = gidx & 255;
        const int h = hg >> 6, g = hg & 63;
        float tc = fminf(fmaxf(temperature[h], 0.1f), 5.0f);
        const float invt = 1.0f / tc;
        float s = 0.f;
        #pragma unroll
        for (int d = 0; d < 32; ++d) s += Wslice[g * 32 + d] * Wx[(h * 32 + d) * 256 + k];
        Wcomb[hg * 256 + k] = f2bf(s * invt);
    } else if (gidx < 131072 + 65536) {
        const int i = gidx - 131072;
        WfxT[i] = f2bf(Wfx[i]);
    } else if (gidx < 131072 + 65536 + 512) {
        const int hg = gidx - 131072 - 65536;
        const int h = hg >> 6, g = hg & 63;
        float tc = fminf(fmaxf(temperature[h], 0.1f), 5.0f);
        float s = bslice[g];
        #pragma unroll
        for (int d = 0; d < 32; ++d) s += Wslice[g * 32 + d] * bx[h * 32 + d];
        bcomb[hg] = s / tc;
    }
}

// ---------------------------------------------------------------------------
// kAB: 256 thr (4 waves = 4 heads), 32-token tiles, grid 1024.
// Block (chunk, hh): heads hh*4..hh*4+3. Pair of a chunk shares an XCD.
// LDS 48KB: [0,16K) x-hi [32][256]bf16, [16K,32K) x-lo, [32K,48K) sw half-img.
// nt loads for x, nt stores for sw/pst/pnorm (keep weights L2-resident).
// ---------------------------------------------------------------------------
__global__ __launch_bounds__(256, 2) void kAB(
    const float* __restrict__ x, const u16* __restrict__ Wcomb,
    const float* __restrict__ bcomb, const u16* __restrict__ WfxT,
    const float* __restrict__ bfx,
    u16* __restrict__ swg, float* __restrict__ pst, float* __restrict__ pnorm)
{
    __shared__ char lds[49152];
    const int tid  = threadIdx.x;
    const int w4   = tid >> 6;
    const int lane = tid & 63;
    const int l15  = lane & 15;
    const int l4   = lane >> 4;
    const int aswz = (l15 & 7) << 4;

    // XCD-pair swizzle: hardware XCD = bid % 8; pair (2c,2c+1) shares one.
    const int bid = blockIdx.x;
    const int gg  = (bid & 7) * 128 + (bid >> 3);
    const int chunk = gg >> 1;
    const int hh    = gg & 1;
    const int head  = hh * 4 + w4;

    float bc[4], bfv[2];
    #pragma unroll
    for (int fc = 0; fc < 4; ++fc) bc[fc] = bcomb[head * 64 + fc * 16 + l15];
    #pragma unroll
    for (int fc = 0; fc < 2; ++fc) bfv[fc] = bfx[head * 32 + fc * 16 + l15];

    f32x4 stacc[2][4];
    #pragma unroll
    for (int i = 0; i < 2; ++i)
        #pragma unroll
        for (int j = 0; j < 4; ++j) stacc[i][j] = (f32x4){0.f, 0.f, 0.f, 0.f};
    float nacc[4] = {0.f, 0.f, 0.f, 0.f};

    const int cnt = 12 + (chunk < 106 ? 1 : 0);    // 512*12+106 = 6250 tiles
    const long tb = (long)chunk * 12 + (chunk < 106 ? chunk : 106);

    // staging: instr j covers row j*4+w4, col = lane (f32x4) — coalesced 1KB
    f32x4 pf[8];
    #pragma unroll
    for (int j = 0; j < 8; ++j)
        pf[j] = __builtin_nontemporal_load(
            (const f32x4*)(x + (size_t)(tb * 32 + j * 4 + w4) * 256 + lane * 4));

    for (int t = 0; t < cnt; ++t) {
        const long tok0 = (tb + t) * 32;

        if (t) {
            __syncthreads();
            // copy out previous sw half-image (16KB), full-line coalesced
            #pragma unroll
            for (int q = 0; q < 4; ++q) {
                const int idx  = q * 4096 + tid * 16;
                const int row  = idx >> 9;
                const int colb = idx & 511;
                const int key  = ((((row >> 2) & 3) ^ (row & 3)) << 4);
                u32x4 v = *(const u32x4*)(lds + 32768 + ((row * 512 + colb) ^ key));
                __builtin_nontemporal_store(v,
                    (u32x4*)((char*)swg + (size_t)(tok0 - 32 + row) * 1024 + (size_t)hh * 512 + colb));
            }
        }
        // stage x hi/lo
        #pragma unroll
        for (int j = 0; j < 8; ++j) {
            const int row = j * 4 + w4;
            unsigned int h0, l0, h1, l1;
            split2(pf[j][0], pf[j][1], h0, l0);
            split2(pf[j][2], pf[j][3], h1, l1);
            const int addr = (row * 512 + lane * 8) ^ ((row & 7) << 4);
            *(u32x2*)(lds + addr)         = (u32x2){h0, h1};
            *(u32x2*)(lds + 16384 + addr) = (u32x2){l0, l1};
        }
        __syncthreads();

        // prefetch next tile early (T14: lands under the MFMA phase)
        if (t + 1 < cnt) {
            #pragma unroll
            for (int j = 0; j < 8; ++j)
                pf[j] = __builtin_nontemporal_load(
                    (const f32x4*)(x + (size_t)(tok0 + 32 + j * 4 + w4) * 256 + lane * 4));
        }

        // merged fx + logits GEMMs over K=256
        f32x4 accF[2][2], accL[2][4];
        #pragma unroll
        for (int mt = 0; mt < 2; ++mt) {
            #pragma unroll
            for (int fc = 0; fc < 2; ++fc)
                accF[mt][fc] = (f32x4){bfv[fc], bfv[fc], bfv[fc], bfv[fc]};
            #pragma unroll
            for (int fc = 0; fc < 4; ++fc)
                accL[mt][fc] = (f32x4){bc[fc], bc[fc], bc[fc], bc[fc]};
        }
        #pragma unroll
        for (int ks = 0; ks < 8; ++ks) {
            bf16x8 bfF[2], bw[4], ah[2], al[2];
            #pragma unroll
            for (int fc = 0; fc < 2; ++fc)
                bfF[fc] = *(const bf16x8*)(WfxT + (size_t)(head * 32 + fc * 16 + l15) * 256 + ks * 32 + l4 * 8);
            #pragma unroll
            for (int fc = 0; fc < 4; ++fc)
                bw[fc] = *(const bf16x8*)(Wcomb + (size_t)(head * 64 + fc * 16 + l15) * 256 + ks * 32 + l4 * 8);
            #pragma unroll
            for (int mt = 0; mt < 2; ++mt) {
                const int off = (mt * 16 + l15) * 512 + ((ks * 64 + l4 * 16) ^ aswz);
                ah[mt] = *(const bf16x8*)(lds + off);
                al[mt] = *(const bf16x8*)(lds + 16384 + off);
            }
            #pragma unroll
            for (int mt = 0; mt < 2; ++mt) {
                #pragma unroll
                for (int fc = 0; fc < 2; ++fc)
                    accF[mt][fc] = MFMA(ah[mt], bfF[fc], accF[mt][fc]);
                #pragma unroll
                for (int fc = 0; fc < 4; ++fc) {
                    accL[mt][fc] = MFMA(ah[mt], bw[fc], accL[mt][fc]);
                    accL[mt][fc] = MFMA(al[mt], bw[fc], accL[mt][fc]);
                }
            }
        }

        // softmax over 64 g: level-order reductions, 8 independent rows/level
        float mrow[8], srow8[8];
        #pragma unroll
        for (int mt = 0; mt < 2; ++mt)
            #pragma unroll
            for (int r = 0; r < 4; ++r) {
                float v0 = accL[mt][0][r], v1 = accL[mt][1][r];
                float v2 = accL[mt][2][r], v3 = accL[mt][3][r];
                mrow[mt * 4 + r] = fmaxf(fmaxf(v0, v1), fmaxf(v2, v3));
            }
        #pragma unroll
        for (int d = 1; d <= 8; d <<= 1)
            #pragma unroll
            for (int i = 0; i < 8; ++i)
                mrow[i] = fmaxf(mrow[i], __shfl_xor(mrow[i], d));
        #pragma unroll
        for (int mt = 0; mt < 2; ++mt)
            #pragma unroll
            for (int r = 0; r < 4; ++r) {
                const int i = mt * 4 + r;
                float e0 = __expf(accL[mt][0][r] - mrow[i]);
                float e1 = __expf(accL[mt][1][r] - mrow[i]);
                float e2 = __expf(accL[mt][2][r] - mrow[i]);
                float e3 = __expf(accL[mt][3][r] - mrow[i]);
                accL[mt][0][r] = e0; accL[mt][1][r] = e1;
                accL[mt][2][r] = e2; accL[mt][3][r] = e3;
                srow8[i] = e0 + e1 + e2 + e3;
            }
        #pragma unroll
        for (int d = 1; d <= 8; d <<= 1)
            #pragma unroll
            for (int i = 0; i < 8; ++i)
                srow8[i] += __shfl_xor(srow8[i], d);
        #pragma unroll
        for (int mt = 0; mt < 2; ++mt)
            #pragma unroll
            for (int r = 0; r < 4; ++r) {
                const int i = mt * 4 + r;
                const float inv = 1.0f / srow8[i];
                float e0 = accL[mt][0][r] * inv, e1 = accL[mt][1][r] * inv;
                float e2 = accL[mt][2][r] * inv, e3 = accL[mt][3][r] * inv;
                accL[mt][0][r] = e0; accL[mt][1][r] = e1;
                accL[mt][2][r] = e2; accL[mt][3][r] = e3;
                nacc[0] += e0; nacc[1] += e1; nacc[2] += e2; nacc[3] += e3;
            }

        // P4: pack sw to bf16 + write swizzled LDS half-image [32][256]
        unsigned int pL[2][4][2];
        #pragma unroll
        for (int mt = 0; mt < 2; ++mt)
            #pragma unroll
            for (int fc = 0; fc < 4; ++fc) {
                u16 w0 = f2bf(accL[mt][fc][0]), w1 = f2bf(accL[mt][fc][1]);
                u16 w2 = f2bf(accL[mt][fc][2]), w3 = f2bf(accL[mt][fc][3]);
                pL[mt][fc][0] = (unsigned int)w0 | ((unsigned int)w1 << 16);
                pL[mt][fc][1] = (unsigned int)w2 | ((unsigned int)w3 << 16);
                const int col2 = (w4 * 64 + fc * 16 + l15) * 2;
                #pragma unroll
                for (int r = 0; r < 4; ++r) {
                    const int nloc = mt * 16 + l4 * 4 + r;
                    const int key  = ((((nloc >> 2) & 3) ^ (nloc & 3)) << 4);
                    const u16 val  = (r == 0) ? w0 : (r == 1) ? w1 : (r == 2) ? w2 : w3;
                    *(u16*)(lds + 32768 + ((nloc * 512 + col2) ^ key)) = val;
                }
            }

        // P5: slice_token partial, pure-register operands (k-permutation trick)
        unsigned int pF[2][2][2];
        #pragma unroll
        for (int mt = 0; mt < 2; ++mt)
            #pragma unroll
            for (int fc = 0; fc < 2; ++fc) {
                pF[mt][fc][0] = pack2(accF[mt][fc][0], accF[mt][fc][1]);
                pF[mt][fc][1] = pack2(accF[mt][fc][2], accF[mt][fc][3]);
            }
        #pragma unroll
        for (int mt2 = 0; mt2 < 2; ++mt2) {
            union { u32x4 u; bf16x8 b; } a;
            a.u = (u32x4){pF[0][mt2][0], pF[0][mt2][1], pF[1][mt2][0], pF[1][mt2][1]};
            #pragma unroll
            for (int nt = 0; nt < 4; ++nt) {
                union { u32x4 u; bf16x8 b; } bb;
                bb.u = (u32x4){pL[0][nt][0], pL[0][nt][1], pL[1][nt][0], pL[1][nt][1]};
                stacc[mt2][nt] = MFMA(a.b, bb.b, stacc[mt2][nt]);
            }
        }
    }

    // final tile sw copy-out
    __syncthreads();
    {
        const long tokL = (tb + cnt - 1) * 32;
        #pragma unroll
        for (int q = 0; q < 4; ++q) {
            const int idx  = q * 4096 + tid * 16;
            const int row  = idx >> 9;
            const int colb = idx & 511;
            const int key  = ((((row >> 2) & 3) ^ (row & 3)) << 4);
            u32x4 v = *(const u32x4*)(lds + 32768 + ((row * 512 + colb) ^ key));
            __builtin_nontemporal_store(v,
                (u32x4*)((char*)swg + (size_t)(tokL + row) * 1024 + (size_t)hh * 512 + colb));
        }
    }

    // epilogue: slice_token partial [head][chunk][2048] + norm partial
    float* pstp = pst + ((size_t)head * 512 + chunk) * 2048;
    #pragma unroll
    for (int mt2 = 0; mt2 < 2; ++mt2)
        #pragma unroll
        for (int nt = 0; nt < 4; ++nt)
            #pragma unroll
            for (int r = 0; r < 4; ++r)
                __builtin_nontemporal_store(stacc[mt2][nt][r],
                    pstp + (mt2 * 16 + l4 * 4 + r) * 64 + nt * 16 + l15);
    #pragma unroll
    for (int fc = 0; fc < 4; ++fc) {
        float v = nacc[fc];
        v += __shfl_xor(v, 16); v += __shfl_xor(v, 32);
        if (l4 == 0)
            __builtin_nontemporal_store(v,
                pnorm + ((size_t)head * 512 + chunk) * 64 + fc * 16 + l15);
    }
}

// ---------------------------------------------------------------------------
// kC1: blocks 0..127: stn[16384] = sum_chunk pst; blocks 128..131: norm[512]
// ---------------------------------------------------------------------------
__global__ __launch_bounds__(256) void kC1(
    const float* __restrict__ pst, const float* __restrict__ pnorm,
    float* __restrict__ stn, float* __restrict__ norm)
{
    __shared__ float red[256];
    const int tid  = threadIdx.x;
    const int half = tid >> 7;
    const int li   = tid & 127;
    if (blockIdx.x < 128) {
        const int o  = blockIdx.x * 128 + li;
        const int h  = o >> 11, oo = o & 2047;
        float s = 0.f;
        for (int b = half * 256; b < half * 256 + 256; ++b)
            s += __builtin_nontemporal_load(pst + ((size_t)h * 512 + b) * 2048 + oo);
        red[tid] = s;
        __syncthreads();
        if (!half) stn[o] = red[li] + red[li + 128];
    } else {
        const int o = (blockIdx.x - 128) * 128 + li;   // 0..511
        const int h = o >> 6, g = o & 63;
        float s = 0.f;
        for (int b = half * 256; b < half * 256 + 256; ++b)
            s += pnorm[((size_t)h * 512 + b) * 64 + g];
        red[tid] = s;
        __syncthreads();
        if (!half) norm[o] = red[li] + red[li + 128];
    }
}

// ---------------------------------------------------------------------------
// kattn: tiny per-head attention over 64 slice tokens
// ---------------------------------------------------------------------------
__global__ __launch_bounds__(64) void kattn(
    const float* __restrict__ stn, const float* __restrict__ norm,
    const float* __restrict__ Wq, const float* __restrict__ Wk,
    const float* __restrict__ Wv, float* __restrict__ os)
{
    __shared__ float kl[2048], vl[2048];
    const int h = blockIdx.x, g = threadIdx.x;
    const float ng = norm[h * 64 + g] + 1e-5f;
    float s[32];
    #pragma unroll
    for (int d = 0; d < 32; ++d) s[d] = stn[h * 2048 + d * 64 + g] / ng;
    float q[32];
    #pragma unroll
    for (int e = 0; e < 32; ++e) {
        float aq = 0.f, ak = 0.f, av = 0.f;
        #pragma unroll
        for (int d = 0; d < 32; ++d) {
            aq += s[d] * Wq[e * 32 + d];
            ak += s[d] * Wk[e * 32 + d];
            av += s[d] * Wv[e * 32 + d];
        }
        q[e] = aq; kl[g * 32 + e] = ak; vl[g * 32 + e] = av;
    }
    __syncthreads();
    float p[64];
    float mx = -1e30f;
    const float scale = 0.17677669529663689f;
    #pragma unroll
    for (int kk = 0; kk < 64; ++kk) {
        float a = 0.f;
        #pragma unroll
        for (int e = 0; e < 32; ++e) a += q[e] * kl[kk * 32 + e];
        a *= scale; p[kk] = a; mx = fmaxf(mx, a);
    }
    float sum = 0.f;
    #pragma unroll
    for (int kk = 0; kk < 64; ++kk) { p[kk] = __expf(p[kk] - mx); sum += p[kk]; }
    const float inv = 1.0f / sum;
    #pragma unroll
    for (int d = 0; d < 32; ++d) {
        float a = 0.f;
        #pragma unroll
        for (int kk = 0; kk < 64; ++kk) a += p[kk] * inv * vl[kk * 32 + d];
        os[h * 2048 + g * 32 + d] = a;
    }
}

// ---------------------------------------------------------------------------
// kD2: Wc2T[co][hg] = sum_d os[h,g,d] * Wout[co, h*32+d]   (bf16)
// ---------------------------------------------------------------------------
__global__ __launch_bounds__(64) void kD2(
    const float* __restrict__ os, const float* __restrict__ Wout,
    u16* __restrict__ Wc2T)
{
    const int co = blockIdx.x;
    for (int rep = 0; rep < 8; ++rep) {
        const int hg = rep * 64 + threadIdx.x;
        const int h = hg >> 6, g = hg & 63;
        float s = 0.f;
        #pragma unroll
        for (int d = 0; d < 32; ++d)
            s += os[h * 2048 + g * 32 + d] * Wout[co * 256 + h * 32 + d];
        Wc2T[co * 512 + hg] = f2bf(s);
    }
}

// ---------------------------------------------------------------------------
// kE: out = sw @ Wc2T^T + bout. Persistent grid 256, B hoisted (128 VGPR),
// LDS double-buffered (128KB) with ONE barrier per tile; nt streams.
// ---------------------------------------------------------------------------
__global__ __launch_bounds__(512, 1) void kE(
    const u16* __restrict__ swg, const u16* __restrict__ Wc2T,
    const float* __restrict__ bout, float* __restrict__ y)
{
    __shared__ char lds[131072];
    const int tid  = threadIdx.x;
    const int w    = tid >> 6;
    const int lane = tid & 63;
    const int l15  = lane & 15;
    const int l4   = lane >> 4;
    const int aswz = (l15 & 7) << 4;

    const int bid = blockIdx.x;
    const int cnt = 12 + (bid < 53 ? 1 : 0);      // 256*12 + 53 = 3125 tiles
    const long tb = (long)bid * 12 + (bid < 53 ? bid : 53);

    bf16x8 Breg[16][2];
    #pragma unroll
    for (int ks = 0; ks < 16; ++ks)
        #pragma unroll
        for (int fc = 0; fc < 2; ++fc)
            Breg[ks][fc] = *(const bf16x8*)(Wc2T +
                (size_t)(w * 32 + fc * 16 + l15) * 512 + ks * 32 + l4 * 8);

    const float b0 = bout[w * 32 + l15], b1 = bout[w * 32 + 16 + l15];

    const int row = tid >> 3, seg = tid & 7;
    const int sbase = row * 1024 + seg * 128;
    const int sswz  = (row & 7) << 4;

    u32x4 pf[8];
    {
        const u32x4* sp = (const u32x4*)(swg + (size_t)(tb * 64 + row) * 512 + seg * 64);
        #pragma unroll
        for (int c = 0; c < 8; ++c) pf[c] = __builtin_nontemporal_load(sp + c);
    }

    for (int t = 0; t < cnt; ++t) {
        const long tok0 = (tb + t) * 64;
        char* buf = lds + ((t & 1) << 16);

        #pragma unroll
        for (int c = 0; c < 8; ++c)
            *(u32x4*)(buf + ((sbase + c * 16) ^ sswz)) = pf[c];
        __syncthreads();

        if (t + 1 < cnt) {
            const u32x4* sp = (const u32x4*)(swg + (size_t)(tok0 + 64 + row) * 512 + seg * 64);
            #pragma unroll
            for (int c = 0; c < 8; ++c) pf[c] = __builtin_nontemporal_load(sp + c);
        }

        f32x4 acc[4][2];
        #pragma unroll
        for (int mt = 0; mt < 4; ++mt) {
            acc[mt][0] = (f32x4){b0, b0, b0, b0};
            acc[mt][1] = (f32x4){b1, b1, b1, b1};
        }

        #pragma unroll
        for (int ks = 0; ks < 16; ++ks) {
            bf16x8 a[4];
            #pragma unroll
            for (int mt = 0; mt < 4; ++mt)
                a[mt] = *(const bf16x8*)(buf + (mt * 16 + l15) * 1024 + ((ks * 64 + l4 * 16) ^ aswz));
            #pragma unroll
            for (int mt = 0; mt < 4; ++mt)
                #pragma unroll
                for (int fc = 0; fc < 2; ++fc)
                    acc[mt][fc] = MFMA(a[mt], Breg[ks][fc], acc[mt][fc]);
        }

        #pragma unroll
        for (int mt = 0; mt < 4; ++mt)
            #pragma unroll
            for (int fc = 0; fc < 2; ++fc)
                #pragma unroll
                for (int r = 0; r < 4; ++r) {
                    const long n = tok0 + mt * 16 + l4 * 4 + r;
                    __builtin_nontemporal_store(acc[mt][fc][r],
                        y + (size_t)n * 256 + w * 32 + fc * 16 + l15);
                }
        // no trailing barrier: next write targets the other buffer
    }
}

// ---------------------------------------------------------------------------
extern "C" void kernel_launch(void* const* d_in, const int* in_sizes, int n_in,
                              void* d_out, int out_size, void* d_ws, size_t ws_size,
                              hipStream_t stream) {
    const float* x       = (const float*)d_in[0];
    const float* Wx      = (const float*)d_in[1];
    const float* bx      = (const float*)d_in[2];
    const float* Wfx     = (const float*)d_in[3];
    const float* bfx     = (const float*)d_in[4];
    const float* Wslice  = (const float*)d_in[5];
    const float* bslice  = (const float*)d_in[6];
    const float* Wq      = (const float*)d_in[7];
    const float* Wk      = (const float*)d_in[8];
    const float* Wv      = (const float*)d_in[9];
    const float* Wout    = (const float*)d_in[10];
    const float* bout    = (const float*)d_in[11];
    const float* temp    = (const float*)d_in[12];

    char* wsb = (char*)d_ws;
    u16*   sw    = (u16*)(wsb);                      // 204,800,000 B
    float* pst   = (float*)(wsb + 204800000);        //  33,554,432 B
    float* pnorm = (float*)(wsb + 238354432);        //   1,048,576 B
    u16*   Wcomb = (u16*)(wsb + 239403008);          //     262,144 B
    float* bcomb = (float*)(wsb + 239665152);        //       2,048 B
    u16*   WfxT  = (u16*)(wsb + 239667200);          //     131,072 B
    u16*   Wc2T  = (u16*)(wsb + 239798272);          //     262,144 B
    float* os    = (float*)(wsb + 240060416);        //      65,536 B
    float* stn   = (float*)(wsb + 240125952);        //      65,536 B
    float* norm  = (float*)(wsb + 240191488);        //       2,048 B
    float* y     = (float*)d_out;

    kprep<<<770, 256, 0, stream>>>(Wx, bx, Wfx, Wslice, bslice, temp, Wcomb, bcomb, WfxT);
    kAB<<<1024, 256, 0, stream>>>(x, Wcomb, bcomb, WfxT, bfx, sw, pst, pnorm);
    kC1<<<132, 256, 0, stream>>>(pst, pnorm, stn, norm);
    kattn<<<8, 64, 0, stream>>>(stn, norm, Wq, Wk, Wv, os);
    kD2<<<256, 64, 0, stream>>>(os, Wout, Wc2T);
    kE<<<256, 512, 0, stream>>>(sw, Wc2T, bout, y);
}

// Round 7
// 648.323 us; speedup vs baseline: 1.5835x; 1.5835x over previous
//
#include <hip/hip_runtime.h>

typedef unsigned short u16;
typedef __attribute__((ext_vector_type(2))) unsigned int u32x2;
typedef __attribute__((ext_vector_type(4))) unsigned int u32x4;
typedef __attribute__((ext_vector_type(4))) float f32x4;
typedef __attribute__((ext_vector_type(8))) short bf16x8;

__device__ __forceinline__ float bf2f(u16 u) {
    union { unsigned int i; float f; } v; v.i = ((unsigned int)u) << 16; return v.f;
}
__device__ __forceinline__ u16 f2bf(float f) {
    union { float f; unsigned int i; } v; v.f = f;
    unsigned int x = v.i;
    return (u16)((x + 0x7fffu + ((x >> 16) & 1u)) >> 16);
}
__device__ __forceinline__ unsigned int pack2(float a, float b) {
    return (unsigned int)f2bf(a) | ((unsigned int)f2bf(b) << 16);
}
__device__ __forceinline__ void split2(float a, float b, unsigned int& h, unsigned int& l) {
    u16 ha = f2bf(a), hb = f2bf(b);
    u16 la = f2bf(a - bf2f(ha)), lb = f2bf(b - bf2f(hb));
    h = (unsigned int)ha | ((unsigned int)hb << 16);
    l = (unsigned int)la | ((unsigned int)lb << 16);
}

__device__ __forceinline__ f32x4 MFMA(bf16x8 a, bf16x8 b, f32x4 c) {
    return __builtin_amdgcn_mfma_f32_16x16x32_bf16(a, b, c, 0, 0, 0);
}

// ---------------------------------------------------------------------------
// kprep: Wcomb[hg][k] = invt_h * sum_d Wslice[g,d]*Wx[h*32+d,k]  (bf16)
//        bcomb[hg]    = invt_h * (sum_d Wslice[g,d]*bx[h*32+d] + bslice[g])
//        WfxT = bf16(Wfx)
// ---------------------------------------------------------------------------
__global__ __launch_bounds__(256) void kprep(
    const float* __restrict__ Wx, const float* __restrict__ bx,
    const float* __restrict__ Wfx, const float* __restrict__ Wslice,
    const float* __restrict__ bslice, const float* __restrict__ temperature,
    u16* __restrict__ Wcomb, float* __restrict__ bcomb, u16* __restrict__ WfxT)
{
    const int gidx = blockIdx.x * 256 + threadIdx.x;
    if (gidx < 131072) {
        const int hg = gidx >> 8, k = gidx & 255;
        const int h = hg >> 6, g = hg & 63;
        float tc = fminf(fmaxf(temperature[h], 0.1f), 5.0f);
        const float invt = 1.0f / tc;
        float s = 0.f;
        #pragma unroll
        for (int d = 0; d < 32; ++d) s += Wslice[g * 32 + d] * Wx[(h * 32 + d) * 256 + k];
        Wcomb[hg * 256 + k] = f2bf(s * invt);
    } else if (gidx < 131072 + 65536) {
        const int i = gidx - 131072;
        WfxT[i] = f2bf(Wfx[i]);
    } else if (gidx < 131072 + 65536 + 512) {
        const int hg = gidx - 131072 - 65536;
        const int h = hg >> 6, g = hg & 63;
        float tc = fminf(fmaxf(temperature[h], 0.1f), 5.0f);
        float s = bslice[g];
        #pragma unroll
        for (int d = 0; d < 32; ++d) s += Wslice[g * 32 + d] * bx[h * 32 + d];
        bcomb[hg] = s / tc;
    }
}

// ---------------------------------------------------------------------------
// kAB v5: WEIGHTS IN LDS. Block = 2 heads (head-pair hp), 512 thr (8 waves):
// wave v: head-local hl=v>>2, token-quarter tq=v&3 (16 tokens of 64-tile).
// LDS 160KB: [0,96K) weights (192 swizzled rows: 128 Wcomb + 64 WfxT),
//            [96K,128K) x-hi [64][256]bf16, [128K,160K) x-lo / sw image.
// Inner loop = pure LDS+MFMA (no global ops). grid 1024 = 256 chunks x 4 hp
// (bid = c*4+hp: all 4 readers of a chunk in the same dispatch round -> L3).
// ---------------------------------------------------------------------------
#define LDS_XH 98304
#define LDS_XL 131072
__global__ __launch_bounds__(512, 2) void kAB(
    const float* __restrict__ x, const u16* __restrict__ Wcomb,
    const float* __restrict__ bcomb, const u16* __restrict__ WfxT,
    const float* __restrict__ bfx,
    u16* __restrict__ swg, float* __restrict__ pst, float* __restrict__ pnorm)
{
    __shared__ char lds[163840];
    const int tid  = threadIdx.x;
    const int wv   = tid >> 6;
    const int lane = tid & 63;
    const int l15  = lane & 15;
    const int l4   = lane >> 4;
    const int hl   = wv >> 2;       // head-local 0..1
    const int tq   = wv & 3;        // token quarter 0..3

    const int bid = blockIdx.x;
    const int c   = bid >> 2;       // chunk 0..255
    const int hp  = bid & 3;        // head-pair 0..3
    const int head = hp * 2 + hl;

    // ---- stage weights once: 192 rows x 512B, XOR-swizzled ----
    for (int u = tid; u < 6144; u += 512) {
        const int row = u >> 5, seg = u & 31;
        const u16* src = (row < 128)
            ? Wcomb + ((size_t)hp * 128 + row) * 256 + seg * 8
            : WfxT  + ((size_t)hp * 64 + (row - 128)) * 256 + seg * 8;
        u32x4 v = *(const u32x4*)src;
        *(u32x4*)(lds + ((row * 512 + seg * 16) ^ ((row & 7) << 4))) = v;
    }

    float bc[4], bfv[2];
    #pragma unroll
    for (int fc = 0; fc < 4; ++fc) bc[fc] = bcomb[head * 64 + fc * 16 + l15];
    #pragma unroll
    for (int fc = 0; fc < 2; ++fc) bfv[fc] = bfx[head * 32 + fc * 16 + l15];

    f32x4 stacc[2][4];
    #pragma unroll
    for (int i = 0; i < 2; ++i)
        #pragma unroll
        for (int j = 0; j < 4; ++j) stacc[i][j] = (f32x4){0.f, 0.f, 0.f, 0.f};
    float nacc[4] = {0.f, 0.f, 0.f, 0.f};

    const int cnt = 12 + (c < 53 ? 1 : 0);     // 256*12 + 53 = 3125 tiles
    const long tb = (long)c * 12 + (c < 53 ? c : 53);

    // x staging: row = tid>>3 (0..63), seg = tid&7; 8 x f32x4 per thread
    const int row = tid >> 3, seg = tid & 7;
    const int xswz = (row & 7) << 4;

    f32x4 pf[8];
    #pragma unroll
    for (int i = 0; i < 8; ++i)
        pf[i] = *(const f32x4*)(x + (size_t)(tb * 64 + row) * 256 + i * 32 + seg * 4);

    const int xrow  = tq * 16 + l15;
    const int xoff  = xrow * 512;
    const int xkey  = (xrow & 7) << 4;
    const int bwrow0 = hl * 64 + l15;          // + fc*16
    const int bfrow0 = 128 + hl * 32 + l15;    // + fc*16

    for (int t = 0; t < cnt; ++t) {
        const long tok0 = (tb + t) * 64;

        __syncthreads();   // A: XL free (prev copy-out done / weights staged)
        // stage x hi/lo
        #pragma unroll
        for (int i = 0; i < 8; ++i) {
            unsigned int h0, l0, h1, l1;
            split2(pf[i][0], pf[i][1], h0, l0);
            split2(pf[i][2], pf[i][3], h1, l1);
            const int a = (row * 512 + i * 64 + seg * 8) ^ xswz;
            *(u32x2*)(lds + LDS_XH + a) = (u32x2){h0, h1};
            *(u32x2*)(lds + LDS_XL + a) = (u32x2){l0, l1};
        }
        __syncthreads();   // B: staging visible

        // pure-LDS GEMMs: fx (hi) + logits (hi+lo), K=256
        f32x4 accF[2], accL[4];
        #pragma unroll
        for (int fc = 0; fc < 2; ++fc) accF[fc] = (f32x4){bfv[fc], bfv[fc], bfv[fc], bfv[fc]};
        #pragma unroll
        for (int fc = 0; fc < 4; ++fc) accL[fc] = (f32x4){bc[fc], bc[fc], bc[fc], bc[fc]};
        #pragma unroll
        for (int ks = 0; ks < 8; ++ks) {
            const int kb = ks * 64 + l4 * 16;
            bf16x8 ah = *(const bf16x8*)(lds + LDS_XH + ((xoff + kb) ^ xkey));
            bf16x8 al = *(const bf16x8*)(lds + LDS_XL + ((xoff + kb) ^ xkey));
            bf16x8 bw[4], bfF[2];
            #pragma unroll
            for (int fc = 0; fc < 4; ++fc) {
                const int r2 = bwrow0 + fc * 16;
                bw[fc] = *(const bf16x8*)(lds + ((r2 * 512 + kb) ^ ((r2 & 7) << 4)));
            }
            #pragma unroll
            for (int fc = 0; fc < 2; ++fc) {
                const int r2 = bfrow0 + fc * 16;
                bfF[fc] = *(const bf16x8*)(lds + ((r2 * 512 + kb) ^ ((r2 & 7) << 4)));
            }
            #pragma unroll
            for (int fc = 0; fc < 2; ++fc) accF[fc] = MFMA(ah, bfF[fc], accF[fc]);
            #pragma unroll
            for (int fc = 0; fc < 4; ++fc) {
                accL[fc] = MFMA(ah, bw[fc], accL[fc]);
                accL[fc] = MFMA(al, bw[fc], accL[fc]);
            }
        }

        // prefetch next x tile (overlaps softmax + barriers)
        if (t + 1 < cnt) {
            #pragma unroll
            for (int i = 0; i < 8; ++i)
                pf[i] = *(const f32x4*)(x + (size_t)(tok0 + 64 + row) * 256 + i * 32 + seg * 4);
        }

        // softmax over 64 g (4 fc regs x 16 lanes), 4 token-rows per lane
        float mrow[4], srow4[4];
        #pragma unroll
        for (int r = 0; r < 4; ++r)
            mrow[r] = fmaxf(fmaxf(accL[0][r], accL[1][r]), fmaxf(accL[2][r], accL[3][r]));
        #pragma unroll
        for (int d = 1; d <= 8; d <<= 1)
            #pragma unroll
            for (int r = 0; r < 4; ++r)
                mrow[r] = fmaxf(mrow[r], __shfl_xor(mrow[r], d));
        #pragma unroll
        for (int r = 0; r < 4; ++r) {
            float e0 = __expf(accL[0][r] - mrow[r]);
            float e1 = __expf(accL[1][r] - mrow[r]);
            float e2 = __expf(accL[2][r] - mrow[r]);
            float e3 = __expf(accL[3][r] - mrow[r]);
            accL[0][r] = e0; accL[1][r] = e1; accL[2][r] = e2; accL[3][r] = e3;
            srow4[r] = e0 + e1 + e2 + e3;
        }
        #pragma unroll
        for (int d = 1; d <= 8; d <<= 1)
            #pragma unroll
            for (int r = 0; r < 4; ++r)
                srow4[r] += __shfl_xor(srow4[r], d);
        #pragma unroll
        for (int r = 0; r < 4; ++r) {
            const float inv = 1.0f / srow4[r];
            float e0 = accL[0][r] * inv, e1 = accL[1][r] * inv;
            float e2 = accL[2][r] * inv, e3 = accL[3][r] * inv;
            accL[0][r] = e0; accL[1][r] = e1; accL[2][r] = e2; accL[3][r] = e3;
            nacc[0] += e0; nacc[1] += e1; nacc[2] += e2; nacc[3] += e3;
        }

        __syncthreads();   // C: all waves done reading XL (x-lo)

        // write sw image [64 tok][128 col] bf16 into XL region
        unsigned int pL[4][2];
        #pragma unroll
        for (int fc = 0; fc < 4; ++fc) {
            u16 w0 = f2bf(accL[fc][0]), w1 = f2bf(accL[fc][1]);
            u16 w2 = f2bf(accL[fc][2]), w3 = f2bf(accL[fc][3]);
            pL[fc][0] = (unsigned int)w0 | ((unsigned int)w1 << 16);
            pL[fc][1] = (unsigned int)w2 | ((unsigned int)w3 << 16);
            const int col2 = (hl * 64 + fc * 16 + l15) * 2;
            #pragma unroll
            for (int r = 0; r < 4; ++r) {
                const int tok = tq * 16 + l4 * 4 + r;
                const u16 val = (r == 0) ? w0 : (r == 1) ? w1 : (r == 2) ? w2 : w3;
                *(u16*)(lds + LDS_XL + ((tok * 256 + col2) ^ ((tok & 7) << 4))) = val;
            }
        }

        // P5: slice_token partial (reg-only, K zero-padded to 16 tokens)
        unsigned int pF[2][2];
        #pragma unroll
        for (int fc = 0; fc < 2; ++fc) {
            pF[fc][0] = pack2(accF[fc][0], accF[fc][1]);
            pF[fc][1] = pack2(accF[fc][2], accF[fc][3]);
        }
        #pragma unroll
        for (int mt2 = 0; mt2 < 2; ++mt2) {
            union { u32x4 u; bf16x8 b; } a;
            a.u = (u32x4){pF[mt2][0], pF[mt2][1], 0u, 0u};
            #pragma unroll
            for (int nt = 0; nt < 4; ++nt) {
                union { u32x4 u; bf16x8 b; } bb;
                bb.u = (u32x4){pL[nt][0], pL[nt][1], 0u, 0u};
                stacc[mt2][nt] = MFMA(a.b, bb.b, stacc[mt2][nt]);
            }
        }

        __syncthreads();   // D: image complete

        // copy-out sw image -> global (coalesced 16B, 256B/token-row chunk)
        #pragma unroll
        for (int q = 0; q < 2; ++q) {
            const int slot = tid * 2 + q;          // 0..1023
            const int tok = slot >> 4, sg = slot & 15;
            u32x4 v = *(const u32x4*)(lds + LDS_XL + ((tok * 256 + sg * 16) ^ ((tok & 7) << 4)));
            __builtin_nontemporal_store(v,
                (u32x4*)(swg + (size_t)(tok0 + tok) * 512 + hp * 128 + sg * 8));
        }
    }

    // ---- epilogue: cross-wave (tq) reduction of stacc / nacc ----
    __syncthreads();
    float* sst = (float*)(lds + LDS_XH);    // [8][2048]
    float* nst = (float*)lds;               // [8][64] (weights dead)
    #pragma unroll
    for (int mt2 = 0; mt2 < 2; ++mt2)
        #pragma unroll
        for (int nt = 0; nt < 4; ++nt)
            #pragma unroll
            for (int r = 0; r < 4; ++r)
                sst[wv * 2048 + (mt2 * 16 + l4 * 4 + r) * 64 + nt * 16 + l15] = stacc[mt2][nt][r];
    #pragma unroll
    for (int fc = 0; fc < 4; ++fc) {
        float v = nacc[fc];
        v += __shfl_xor(v, 16); v += __shfl_xor(v, 32);
        if (l4 == 0) nst[wv * 64 + fc * 16 + l15] = v;
    }
    __syncthreads();
    for (int i = tid; i < 4096; i += 512) {
        const int hl2 = i >> 11, e = i & 2047;
        float s = sst[(hl2 * 4 + 0) * 2048 + e] + sst[(hl2 * 4 + 1) * 2048 + e]
                + sst[(hl2 * 4 + 2) * 2048 + e] + sst[(hl2 * 4 + 3) * 2048 + e];
        __builtin_nontemporal_store(s,
            pst + ((size_t)(hp * 2 + hl2) * 256 + c) * 2048 + e);
    }
    if (tid < 128) {
        const int hl2 = tid >> 6, g = tid & 63;
        float s = nst[(hl2 * 4 + 0) * 64 + g] + nst[(hl2 * 4 + 1) * 64 + g]
                + nst[(hl2 * 4 + 2) * 64 + g] + nst[(hl2 * 4 + 3) * 64 + g];
        pnorm[((size_t)(hp * 2 + hl2) * 256 + c) * 64 + g] = s;
    }
}

// ---------------------------------------------------------------------------
// kC1: blocks 0..127: stn[16384] = sum_chunk pst; blocks 128..131: norm[512]
// ---------------------------------------------------------------------------
__global__ __launch_bounds__(256) void kC1(
    const float* __restrict__ pst, const float* __restrict__ pnorm,
    float* __restrict__ stn, float* __restrict__ norm)
{
    __shared__ float red[256];
    const int tid  = threadIdx.x;
    const int half = tid >> 7;
    const int li   = tid & 127;
    if (blockIdx.x < 128) {
        const int o  = blockIdx.x * 128 + li;
        const int h  = o >> 11, oo = o & 2047;
        float s = 0.f;
        for (int b = half * 128; b < half * 128 + 128; ++b)
            s += __builtin_nontemporal_load(pst + ((size_t)h * 256 + b) * 2048 + oo);
        red[tid] = s;
        __syncthreads();
        if (!half) stn[o] = red[li] + red[li + 128];
    } else {
        const int o = (blockIdx.x - 128) * 128 + li;   // 0..511
        const int h = o >> 6, g = o & 63;
        float s = 0.f;
        for (int b = half * 128; b < half * 128 + 128; ++b)
            s += pnorm[((size_t)h * 256 + b) * 64 + g];
        red[tid] = s;
        __syncthreads();
        if (!half) norm[o] = red[li] + red[li + 128];
    }
}

// ---------------------------------------------------------------------------
// kattn: tiny per-head attention over 64 slice tokens
// ---------------------------------------------------------------------------
__global__ __launch_bounds__(64) void kattn(
    const float* __restrict__ stn, const float* __restrict__ norm,
    const float* __restrict__ Wq, const float* __restrict__ Wk,
    const float* __restrict__ Wv, float* __restrict__ os)
{
    __shared__ float kl[2048], vl[2048];
    const int h = blockIdx.x, g = threadIdx.x;
    const float ng = norm[h * 64 + g] + 1e-5f;
    float s[32];
    #pragma unroll
    for (int d = 0; d < 32; ++d) s[d] = stn[h * 2048 + d * 64 + g] / ng;
    float q[32];
    #pragma unroll
    for (int e = 0; e < 32; ++e) {
        float aq = 0.f, ak = 0.f, av = 0.f;
        #pragma unroll
        for (int d = 0; d < 32; ++d) {
            aq += s[d] * Wq[e * 32 + d];
            ak += s[d] * Wk[e * 32 + d];
            av += s[d] * Wv[e * 32 + d];
        }
        q[e] = aq; kl[g * 32 + e] = ak; vl[g * 32 + e] = av;
    }
    __syncthreads();
    float p[64];
    float mx = -1e30f;
    const float scale = 0.17677669529663689f;
    #pragma unroll
    for (int kk = 0; kk < 64; ++kk) {
        float a = 0.f;
        #pragma unroll
        for (int e = 0; e < 32; ++e) a += q[e] * kl[kk * 32 + e];
        a *= scale; p[kk] = a; mx = fmaxf(mx, a);
    }
    float sum = 0.f;
    #pragma unroll
    for (int kk = 0; kk < 64; ++kk) { p[kk] = __expf(p[kk] - mx); sum += p[kk]; }
    const float inv = 1.0f / sum;
    #pragma unroll
    for (int d = 0; d < 32; ++d) {
        float a = 0.f;
        #pragma unroll
        for (int kk = 0; kk < 64; ++kk) a += p[kk] * inv * vl[kk * 32 + d];
        os[h * 2048 + g * 32 + d] = a;
    }
}

// ---------------------------------------------------------------------------
// kD2: Wc2T[co][hg] = sum_d os[h,g,d] * Wout[co, h*32+d]   (bf16)
// ---------------------------------------------------------------------------
__global__ __launch_bounds__(64) void kD2(
    const float* __restrict__ os, const float* __restrict__ Wout,
    u16* __restrict__ Wc2T)
{
    const int co = blockIdx.x;
    for (int rep = 0; rep < 8; ++rep) {
        const int hg = rep * 64 + threadIdx.x;
        const int h = hg >> 6, g = hg & 63;
        float s = 0.f;
        #pragma unroll
        for (int d = 0; d < 32; ++d)
            s += os[h * 2048 + g * 32 + d] * Wout[co * 256 + h * 32 + d];
        Wc2T[co * 512 + hg] = f2bf(s);
    }
}

// ---------------------------------------------------------------------------
// kE: out = sw @ Wc2T^T + bout. Persistent grid 256, B hoisted (128 VGPR),
// LDS double-buffered (128KB) with ONE barrier per tile; nt streams.
// ---------------------------------------------------------------------------
__global__ __launch_bounds__(512, 1) void kE(
    const u16* __restrict__ swg, const u16* __restrict__ Wc2T,
    const float* __restrict__ bout, float* __restrict__ y)
{
    __shared__ char lds[131072];
    const int tid  = threadIdx.x;
    const int w    = tid >> 6;
    const int lane = tid & 63;
    const int l15  = lane & 15;
    const int l4   = lane >> 4;
    const int aswz = (l15 & 7) << 4;

    const int bid = blockIdx.x;
    const int cnt = 12 + (bid < 53 ? 1 : 0);      // 256*12 + 53 = 3125 tiles
    const long tb = (long)bid * 12 + (bid < 53 ? bid : 53);

    bf16x8 Breg[16][2];
    #pragma unroll
    for (int ks = 0; ks < 16; ++ks)
        #pragma unroll
        for (int fc = 0; fc < 2; ++fc)
            Breg[ks][fc] = *(const bf16x8*)(Wc2T +
                (size_t)(w * 32 + fc * 16 + l15) * 512 + ks * 32 + l4 * 8);

    const float b0 = bout[w * 32 + l15], b1 = bout[w * 32 + 16 + l15];

    const int row = tid >> 3, seg = tid & 7;
    const int sbase = row * 1024 + seg * 128;
    const int sswz  = (row & 7) << 4;

    u32x4 pf[8];
    {
        const u32x4* sp = (const u32x4*)(swg + (size_t)(tb * 64 + row) * 512 + seg * 64);
        #pragma unroll
        for (int c = 0; c < 8; ++c) pf[c] = __builtin_nontemporal_load(sp + c);
    }

    for (int t = 0; t < cnt; ++t) {
        const long tok0 = (tb + t) * 64;
        char* buf = lds + ((t & 1) << 16);

        #pragma unroll
        for (int c = 0; c < 8; ++c)
            *(u32x4*)(buf + ((sbase + c * 16) ^ sswz)) = pf[c];
        __syncthreads();

        if (t + 1 < cnt) {
            const u32x4* sp = (const u32x4*)(swg + (size_t)(tok0 + 64 + row) * 512 + seg * 64);
            #pragma unroll
            for (int c = 0; c < 8; ++c) pf[c] = __builtin_nontemporal_load(sp + c);
        }

        f32x4 acc[4][2];
        #pragma unroll
        for (int mt = 0; mt < 4; ++mt) {
            acc[mt][0] = (f32x4){b0, b0, b0, b0};
            acc[mt][1] = (f32x4){b1, b1, b1, b1};
        }

        #pragma unroll
        for (int ks = 0; ks < 16; ++ks) {
            bf16x8 a[4];
            #pragma unroll
            for (int mt = 0; mt < 4; ++mt)
                a[mt] = *(const bf16x8*)(buf + (mt * 16 + l15) * 1024 + ((ks * 64 + l4 * 16) ^ aswz));
            #pragma unroll
            for (int mt = 0; mt < 4; ++mt)
                #pragma unroll
                for (int fc = 0; fc < 2; ++fc)
                    acc[mt][fc] = MFMA(a[mt], Breg[ks][fc], acc[mt][fc]);
        }

        #pragma unroll
        for (int mt = 0; mt < 4; ++mt)
            #pragma unroll
            for (int fc = 0; fc < 2; ++fc)
                #pragma unroll
                for (int r = 0; r < 4; ++r) {
                    const long n = tok0 + mt * 16 + l4 * 4 + r;
                    __builtin_nontemporal_store(acc[mt][fc][r],
                        y + (size_t)n * 256 + w * 32 + fc * 16 + l15);
                }
        // no trailing barrier: next write targets the other buffer
    }
}

// ---------------------------------------------------------------------------
extern "C" void kernel_launch(void* const* d_in, const int* in_sizes, int n_in,
                              void* d_out, int out_size, void* d_ws, size_t ws_size,
                              hipStream_t stream) {
    const float* x       = (const float*)d_in[0];
    const float* Wx      = (const float*)d_in[1];
    const float* bx      = (const float*)d_in[2];
    const float* Wfx     = (const float*)d_in[3];
    const float* bfx     = (const float*)d_in[4];
    const float* Wslice  = (const float*)d_in[5];
    const float* bslice  = (const float*)d_in[6];
    const float* Wq      = (const float*)d_in[7];
    const float* Wk      = (const float*)d_in[8];
    const float* Wv      = (const float*)d_in[9];
    const float* Wout    = (const float*)d_in[10];
    const float* bout    = (const float*)d_in[11];
    const float* temp    = (const float*)d_in[12];

    char* wsb = (char*)d_ws;
    u16*   sw    = (u16*)(wsb);                      // 204,800,000 B
    float* pst   = (float*)(wsb + 204800000);        //  16,777,216 B
    float* pnorm = (float*)(wsb + 238354432);        //     524,288 B
    u16*   Wcomb = (u16*)(wsb + 239403008);          //     262,144 B
    float* bcomb = (float*)(wsb + 239665152);        //       2,048 B
    u16*   WfxT  = (u16*)(wsb + 239667200);          //     131,072 B
    u16*   Wc2T  = (u16*)(wsb + 239798272);          //     262,144 B
    float* os    = (float*)(wsb + 240060416);        //      65,536 B
    float* stn   = (float*)(wsb + 240125952);        //      65,536 B
    float* norm  = (float*)(wsb + 240191488);        //       2,048 B
    float* y     = (float*)d_out;

    kprep<<<770, 256, 0, stream>>>(Wx, bx, Wfx, Wslice, bslice, temp, Wcomb, bcomb, WfxT);
    kAB<<<1024, 512, 0, stream>>>(x, Wcomb, bcomb, WfxT, bfx, sw, pst, pnorm);
    kC1<<<132, 256, 0, stream>>>(pst, pnorm, stn, norm);
    kattn<<<8, 64, 0, stream>>>(stn, norm, Wq, Wk, Wv, os);
    kD2<<<256, 64, 0, stream>>>(os, Wout, Wc2T);
    kE<<<256, 512, 0, stream>>>(sw, Wc2T, bout, y);
}